// Round 9
// baseline (273.315 us; speedup 1.0000x reference)
//
#include <hip/hip_runtime.h>
#include <hip/hip_bf16.h>
#include <math.h>

#define N_NODES 100000
#define N_EDGES 1600000
#define NEG_SLOPE 0.2f

// bucket = dst >> 7 : 128 nodes per bucket, contiguous node ranges
#define NB_BUCKET 782            // ceil(100000 / 128)
#define ST_CAP 2560              // fixed bucket stride AND LDS cap (mean 2048, 11 sigma)

// ---- workspace layout (bytes) ----
#define OFF_H     0              // N*128 bf16 = 25,600,000
#define OFF_ASRC  25600000       // N*4 f32    =  1,600,000
#define OFF_ADST  27200000       // N*4 f32    =  1,600,000
#define OFF_NODE  28800000       // N int2     =    800,000 (start, deg)
#define OFF_BCUR  29600000       // 782 int (pad 4096)
#define OFF_TMP   29604096       // 782*2560*4 = 8,007,680 (tmp AND csr, in-place)
#define OFF_WHT   37611776       // 128*128 bf16 = 32,768  (W^T hi)
#define OFF_WLT   37644544       // 128*128 bf16 = 32,768  (W^T lo residual)
#define OFF_WAH   37677312       // 16*128 bf16 = 4,096    (WA^T hi, rows 8-15 zero)
#define OFF_WAL   37681408       // 16*128 bf16 = 4,096    (WA^T lo)
// total ≈ 37.7 MB

typedef __attribute__((ext_vector_type(8))) __bf16 bf16x8;
typedef __attribute__((ext_vector_type(4))) float  f32x4;
union BF8 { unsigned u32[4]; bf16x8 v; };

__device__ __forceinline__ float leaky(float x) {
    return fmaxf(x, NEG_SLOPE * x);
}
__device__ __forceinline__ float sel4(int h, float a, float b, float c, float d) {
    return h == 0 ? a : (h == 1 ? b : (h == 2 ? c : d));
}
// bf16x2 (packed in a uint) -> float2; .x = low half (even channel)
__device__ __forceinline__ float2 bf2_to_f2(unsigned int u) {
    float2 r;
    r.x = __uint_as_float(u << 16);
    r.y = __uint_as_float(u & 0xffff0000u);
    return r;
}
// round-to-nearest-even fp32 -> bf16 bits
__device__ __forceinline__ unsigned bf16_rne(float f) {
    const unsigned b = __float_as_uint(f);
    return ((b + 0x7FFFu + ((b >> 16) & 1u)) >> 16) & 0xFFFFu;
}
__device__ __forceinline__ float bf16_tof(unsigned hb) {
    return __uint_as_float(hb << 16);
}
// wave-local LDS fence: stage[] slices are per-wave, no block barrier needed
__device__ __forceinline__ void wave_lds_fence() {
    asm volatile("s_waitcnt lgkmcnt(0)" ::: "memory");
    __builtin_amdgcn_sched_barrier(0);
}

// ---------------------------------------------------------------------------
// K0: W prep — (a) split W into bf16 hi/lo, transpose to [n][k];
// (b) WA = W @ Att (cols 0-3 = att_src heads, 4-7 = att_dst heads);
// (c) zero bcur.
// ---------------------------------------------------------------------------
__global__ __launch_bounds__(256) void wprep_kernel(
    const float* __restrict__ W, const float* __restrict__ att_src,
    const float* __restrict__ att_dst,
    ushort* __restrict__ WhT, ushort* __restrict__ WlT,
    ushort* __restrict__ WAh, ushort* __restrict__ WAl,
    int* __restrict__ bcur)
{
    const int idx = blockIdx.x * 256 + threadIdx.x;   // 0..16383
    const int n = idx >> 7, k = idx & 127;
    const float w  = W[k * 128 + n];
    const unsigned hb = bf16_rne(w);
    const float rs = w - bf16_tof(hb);
    WhT[n * 128 + k] = (ushort)hb;
    WlT[n * 128 + k] = (ushort)bf16_rne(rs);

    if (idx < 2048) {                                  // WA^T: j = 0..15, k
        const int j = idx >> 7;                        // WA column
        float v = 0.f;
        if (j < 8) {
            const int hh = j & 3;
            const float* att = (j < 4) ? att_src : att_dst;
#pragma unroll
            for (int c = 0; c < 32; ++c)
                v = fmaf(W[k * 128 + hh * 32 + c], att[hh * 32 + c], v);
        }
        const unsigned ab = bf16_rne(v);
        WAh[j * 128 + k] = (ushort)ab;
        WAl[j * 128 + k] = (ushort)bf16_rne(v - bf16_tof(ab));
    }
    if (idx < NB_BUCKET) bcur[idx] = 0;
}

// ---------------------------------------------------------------------------
// K1 (FAT): interleaved scat + gemm blocks (data-independent, overlap on
// the device). Every 4th block (bid%4==3, bid>>2 < 512) runs scat; the
// rest run gemm. Low register footprint (16 rows/wave, per-ks fragment
// staging) + tiny LDS -> 4 blocks/CU for latency hiding.
// ---------------------------------------------------------------------------
#define S1_EPB 3125
#define N_SCAT 512
#define N_GEMM 1563              // ceil(100000 / 64)
#define FAT_BLOCKS 2075          // N_SCAT + N_GEMM

__global__ __launch_bounds__(256, 4) void fat_kernel(
    // gemm
    const float* __restrict__ x, const ushort* __restrict__ WhT,
    const ushort* __restrict__ WlT, const ushort* __restrict__ WAh,
    const ushort* __restrict__ WAl,
    ushort* __restrict__ h_u16, float* __restrict__ a_src, float* __restrict__ a_dst,
    // scat
    const int* __restrict__ src, const int* __restrict__ dst,
    int* __restrict__ bcur, unsigned int* __restrict__ tmp)
{
    __shared__ int s_cnt[NB_BUCKET];       // scat only (3.1 KB)

    const int bid = blockIdx.x;
    const int tid = threadIdx.x;

    if ((bid & 3) == 3 && (bid >> 2) < N_SCAT) {
        // ---------------- scat body (R5 logic, no dstash) ----------------
        for (int i = tid; i < NB_BUCKET; i += 256) s_cnt[i] = 0;
        __syncthreads();
        const int e0 = (bid >> 2) * S1_EPB;
        // pass 1: local histogram
        for (int i = tid; i < S1_EPB; i += 256)
            atomicAdd(&s_cnt[dst[e0 + i] >> 7], 1);
        __syncthreads();
        // claim contiguous chunks in each bucket (bucket-relative base)
        for (int b = tid; b < NB_BUCKET; b += 256) {
            const int c = s_cnt[b];
            s_cnt[b] = c ? (b * ST_CAP + atomicAdd(&bcur[b], c)) : 0;
        }
        __syncthreads();
        // pass 2: place edges (dst re-read, L2-hot)
        for (int i = tid; i < S1_EPB; i += 256) {
            const int d = dst[e0 + i];
            const int s = src[e0 + i];
            const int p = atomicAdd(&s_cnt[d >> 7], 1);
            tmp[p] = ((unsigned int)s << 7) | (unsigned int)(d & 127);
        }
        return;
    }

    // -------------------- gemm body: 16 rows/wave, 64 rows/block ----------
    const int gid  = (bid < 2048) ? bid - ((bid + 1) >> 2) : bid - N_SCAT;
    const int wv   = tid >> 6;
    const int lane = tid & 63;
    const int c15  = lane & 15;
    const int kg   = lane >> 4;               // k-octet group 0..3
    const int r0   = gid * 64 + wv * 16;      // wave's 16 rows

    int rowl = r0 + c15;
    rowl = rowl < N_NODES ? rowl : N_NODES - 1;
    const float4* xp = (const float4*)&x[(size_t)rowl * 128];

    f32x4 acc[8];
    f32x4 acca = (f32x4){0.f, 0.f, 0.f, 0.f};
#pragma unroll
    for (int nt = 0; nt < 8; ++nt)
        acc[nt] = (f32x4){0.f, 0.f, 0.f, 0.f};

#pragma unroll
    for (int ks = 0; ks < 4; ++ks) {
        const int kb = ks * 32 + kg * 8;
        // stage this K-step's A-fragment (hi/lo) — transient registers
        const float4 fa = xp[kb >> 2];
        const float4 fb = xp[(kb >> 2) + 1];
        const float f[8] = {fa.x, fa.y, fa.z, fa.w, fb.x, fb.y, fb.z, fb.w};
        BF8 H, L;
#pragma unroll
        for (int j = 0; j < 4; ++j) {
            const unsigned h0 = bf16_rne(f[2 * j + 0]);
            const unsigned h1 = bf16_rne(f[2 * j + 1]);
            const unsigned l0 = bf16_rne(f[2 * j + 0] - bf16_tof(h0));
            const unsigned l1 = bf16_rne(f[2 * j + 1] - bf16_tof(h1));
            H.u32[j] = h0 | (h1 << 16);
            L.u32[j] = l0 | (l1 << 16);
        }
        const bf16x8 ah = H.v;
        const bf16x8 al = L.v;

#pragma unroll
        for (int nt = 0; nt < 8; ++nt) {
            const int col = nt * 16 + c15;
            const bf16x8 bh = *(const bf16x8*)&WhT[col * 128 + kb];
            const bf16x8 bl = *(const bf16x8*)&WlT[col * 128 + kb];
            acc[nt] = __builtin_amdgcn_mfma_f32_16x16x32_bf16(ah, bh, acc[nt], 0, 0, 0);
            acc[nt] = __builtin_amdgcn_mfma_f32_16x16x32_bf16(al, bh, acc[nt], 0, 0, 0);
            acc[nt] = __builtin_amdgcn_mfma_f32_16x16x32_bf16(ah, bl, acc[nt], 0, 0, 0);
        }
        // attention columns (8 live cols in a 16-wide fragment)
        const bf16x8 bha = *(const bf16x8*)&WAh[c15 * 128 + kb];
        const bf16x8 bla = *(const bf16x8*)&WAl[c15 * 128 + kb];
        acca = __builtin_amdgcn_mfma_f32_16x16x32_bf16(ah, bha, acca, 0, 0, 0);
        acca = __builtin_amdgcn_mfma_f32_16x16x32_bf16(al, bha, acca, 0, 0, 0);
        acca = __builtin_amdgcn_mfma_f32_16x16x32_bf16(ah, bla, acca, 0, 0, 0);
    }

    // ---- epilogue: h bf16 stores + direct a_src/a_dst stores ----
    // C/D layout: col = nt*16 + (lane&15), row = (lane>>4)*4 + reg
#pragma unroll
    for (int reg = 0; reg < 4; ++reg) {
        const int row = r0 + kg * 4 + reg;
        if (row >= N_NODES) continue;
#pragma unroll
        for (int nt = 0; nt < 8; ++nt)
            h_u16[(size_t)row * 128 + nt * 16 + c15] =
                (ushort)bf16_rne(acc[nt][reg]);
        if (c15 < 4)
            a_src[row * 4 + c15] = acca[reg];
        else if (c15 < 8)
            a_dst[row * 4 + (c15 - 4)] = acca[reg];
    }
}

// ---------------------------------------------------------------------------
// K2: per-bucket finalize. One block per bucket: full LDS stage (cnt<=ST_CAP)
// + node hist + in-block scan -> node_info{start,deg} AND IN-PLACE csr
// scatter over the tmp region (all reads complete before writes).
// ---------------------------------------------------------------------------
__global__ __launch_bounds__(256) void phaseB_kernel(
    const unsigned int* __restrict__ tmp, const int* __restrict__ bcur,
    int2* __restrict__ node_info, int* __restrict__ csr)
{
    __shared__ unsigned int st[ST_CAP];
    __shared__ int hist[128];
    __shared__ int cur[128];
    __shared__ int wtot[4];

    const int b    = blockIdx.x;
    const int tid  = threadIdx.x;
    const int lane = tid & 63;
    const int wv   = tid >> 6;
    const int base = b * ST_CAP;
    int cnt = bcur[b];
    cnt = cnt < ST_CAP ? cnt : ST_CAP;

    if (tid < 128) hist[tid] = 0;
    __syncthreads();

    // stage (everything fits) + histogram
    for (int i = tid; i < cnt; i += 256) {
        const unsigned int v = tmp[base + i];
        st[i] = v;
        atomicAdd(&hist[v & 127], 1);
    }
    __syncthreads();

    // exclusive scan of 128 bins across first 2 waves (uniform barriers)
    const int hv = (tid < 128) ? hist[tid] : 0;
    int sv = hv;
#pragma unroll
    for (int off = 1; off < 64; off <<= 1) {
        int u = __shfl_up(sv, off);
        if (lane >= off) sv += u;
    }
    if (lane == 63) wtot[wv] = sv;
    __syncthreads();
    const int wpre = (wv > 0 ? wtot[0] : 0) + (wv > 1 ? wtot[1] : 0) + (wv > 2 ? wtot[2] : 0);
    if (tid < 128) {
        const int excl = wpre + sv - hv;
        cur[tid] = excl;
        const int node = (b << 7) + tid;
        if (node < N_NODES) node_info[node] = make_int2(base + excl, hv);
    }
    __syncthreads();

    // scatter src into bucket-local csr region (in-place over tmp: safe,
    // all tmp reads for this bucket completed before the barrier above)
    for (int i = tid; i < cnt; i += 256) {
        const unsigned int v = st[i];
        const int p = atomicAdd(&cur[v & 127], 1);
        csr[base + p] = (int)(v >> 7);
    }
}

// ---------------------------------------------------------------------------
// K3: fused softmax + aggregate + ELU (v2 structure — best measured).
// ---------------------------------------------------------------------------
__global__ __launch_bounds__(256, 4) void gat_agg_kernel(
    const int* __restrict__ csr_src, const int2* __restrict__ node_info,
    const __hip_bfloat162* __restrict__ h_bf,
    const float* __restrict__ a_src, const float* __restrict__ a_dst,
    const float* __restrict__ bias, float* __restrict__ out)
{
    __shared__ float4 stage[4][128];

    const int wv   = threadIdx.x >> 6;
    const int lane = threadIdx.x & 63;
    const int node = blockIdx.x * 4 + wv;

    const int2 nf  = node_info[node];
    const int start = nf.x;
    const int deg   = nf.y;

    const float4 ad4 = ((const float4*)a_dst)[node];

    // stage (s, e_head) pairs for up to 64 edges; zeros beyond deg
    float sf = __int_as_float(0);
    float e0 = 0.f, e1 = 0.f, e2 = 0.f, e3 = 0.f;
    if (lane < deg) {
        const int s = csr_src[start + lane];
        sf = __int_as_float(s);
        const float4 as4 = ((const float4*)a_src)[s];
        e0 = __expf(leaky(as4.x + ad4.x));
        e1 = __expf(leaky(as4.y + ad4.y));
        e2 = __expf(leaky(as4.z + ad4.z));
        e3 = __expf(leaky(as4.w + ad4.w));
    }
    stage[wv][lane * 2 + 0] = make_float4(sf, e0, sf, e1);
    stage[wv][lane * 2 + 1] = make_float4(sf, e2, sf, e3);
    wave_lds_fence();

    if (deg <= 64) {
        const int qw   = lane >> 4;        // edge group 0..3
        const int cpos = lane & 15;        // 8-channel slot within row
        const int hsub = cpos >> 2;        // head of this lane's channels
        const float2* sp = (const float2*)&stage[wv][0];
        const uint4*  hp = (const uint4*)h_bf;

        float acc[8];
#pragma unroll
        for (int i = 0; i < 8; ++i) acc[i] = 0.f;
        float den = 0.f;

        // 16 edges per iteration; je = j + u*4 + qw <= 63 always (deg<=64)
        for (int j = 0; j < deg; j += 16) {
#pragma unroll
            for (int u = 0; u < 4; ++u) {
                const float2 se = sp[(j + u * 4 + qw) * 4 + hsub];
                const float ev = se.y;
                const unsigned s = (unsigned)__float_as_int(se.x);
                const uint4 hv = hp[(size_t)(s * 16u + (unsigned)cpos)];
                float2 f;
                f = bf2_to_f2(hv.x);
                acc[0] = fmaf(ev, f.x, acc[0]);
                acc[1] = fmaf(ev, f.y, acc[1]);
                f = bf2_to_f2(hv.y);
                acc[2] = fmaf(ev, f.x, acc[2]);
                acc[3] = fmaf(ev, f.y, acc[3]);
                f = bf2_to_f2(hv.z);
                acc[4] = fmaf(ev, f.x, acc[4]);
                acc[5] = fmaf(ev, f.y, acc[5]);
                f = bf2_to_f2(hv.w);
                acc[6] = fmaf(ev, f.x, acc[6]);
                acc[7] = fmaf(ev, f.y, acc[7]);
                den += ev;
            }
        }

        // combine the 4 edge-groups (lanes differ in bits 4,5)
#pragma unroll
        for (int i = 0; i < 8; ++i) acc[i] += __shfl_xor(acc[i], 16);
#pragma unroll
        for (int i = 0; i < 8; ++i) acc[i] += __shfl_xor(acc[i], 32);
        den += __shfl_xor(den, 16);
        den += __shfl_xor(den, 32);

        // normalize before redistribution (den is per-head = per-cpos-group)
        const float inv = 1.0f / (den + 1e-16f);
#pragma unroll
        for (int i = 0; i < 8; ++i) acc[i] *= inv;

        // redistribute 8-ch-per-lane -> 2-ch-per-lane via wave-local LDS
        if (qw == 0) {
            float4* sf4 = (float4*)&stage[wv][0];
            sf4[cpos * 2 + 0] = make_float4(acc[0], acc[1], acc[2], acc[3]);
            sf4[cpos * 2 + 1] = make_float4(acc[4], acc[5], acc[6], acc[7]);
        }
        wave_lds_fence();
        const float2 v  = ((const float2*)&stage[wv][0])[lane];
        const float2 b2 = ((const float2*)bias)[lane];
        float ox = v.x + b2.x;
        float oy = v.y + b2.y;
        ox = ox > 0.f ? ox : __expf(ox) - 1.f;
        oy = oy > 0.f ? oy : __expf(oy) - 1.f;
        ((float2*)out)[(size_t)node * 64 + lane] = make_float2(ox, oy);
    } else {
        // rare fallback: deg > 64
        const int hidx = lane >> 4;
        const float adh = sel4(hidx, ad4.x, ad4.y, ad4.z, ad4.w);
        float2 acc = {0.f, 0.f};
        float  den = 0.f;
        for (int j = 0; j < deg; ++j) {
            const int s = csr_src[start + j];
            const float ash = a_src[s * 4 + hidx];
            const float ex = __expf(leaky(ash + adh));
            const float2 f = __bfloat1622float2(h_bf[(size_t)s * 64 + lane]);
            acc.x += ex * f.x;
            acc.y += ex * f.y;
            den   += ex;
        }
        const float inv = 1.0f / (den + 1e-16f);
        const float2 b2 = ((const float2*)bias)[lane];
        float ox = acc.x * inv + b2.x;
        float oy = acc.y * inv + b2.y;
        ox = ox > 0.f ? ox : expm1f(ox);
        oy = oy > 0.f ? oy : expm1f(oy);
        ((float2*)out)[(size_t)node * 64 + lane] = make_float2(ox, oy);
    }
}

// ---------------------------------------------------------------------------
extern "C" void kernel_launch(void* const* d_in, const int* in_sizes, int n_in,
                              void* d_out, int out_size, void* d_ws, size_t ws_size,
                              hipStream_t stream)
{
    const float* x       = (const float*)d_in[0];
    const int*   ei      = (const int*)  d_in[1];
    const float* W       = (const float*)d_in[2];
    const float* att_src = (const float*)d_in[3];
    const float* att_dst = (const float*)d_in[4];
    const float* bias    = (const float*)d_in[5];
    float*       out     = (float*)d_out;

    char* ws = (char*)d_ws;
    ushort* h_u16 = (ushort*)(ws + OFF_H);
    __hip_bfloat162* h_bf = (__hip_bfloat162*)(ws + OFF_H);
    float* a_src = (float*)(ws + OFF_ASRC);
    float* a_dst = (float*)(ws + OFF_ADST);
    int2*  ninfo = (int2*) (ws + OFF_NODE);
    int*   bcur  = (int*)  (ws + OFF_BCUR);
    unsigned int* tmp = (unsigned int*)(ws + OFF_TMP);
    int*   csr   = (int*)  (ws + OFF_TMP);   // in-place: csr overwrites tmp
    ushort* WhT  = (ushort*)(ws + OFF_WHT);
    ushort* WlT  = (ushort*)(ws + OFF_WLT);
    ushort* WAh  = (ushort*)(ws + OFF_WAH);
    ushort* WAl  = (ushort*)(ws + OFF_WAL);

    const int* srcp = ei;
    const int* dstp = ei + N_EDGES;

    wprep_kernel<<<64, 256, 0, stream>>>(W, att_src, att_dst, WhT, WlT, WAh, WAl, bcur);

    fat_kernel<<<FAT_BLOCKS, 256, 0, stream>>>(
        x, WhT, WlT, WAh, WAl, h_u16, a_src, a_dst,
        srcp, dstp, bcur, tmp);

    phaseB_kernel<<<NB_BUCKET, 256, 0, stream>>>(tmp, bcur, ninfo, csr);

    gat_agg_kernel<<<N_NODES / 4, 256, 0, stream>>>(
        csr, ninfo, h_bf, a_src, a_dst, bias, out);
}

// Round 10
// 267.993 us; speedup vs baseline: 1.0199x; 1.0199x over previous
//
#include <hip/hip_runtime.h>
#include <hip/hip_bf16.h>
#include <math.h>

#define N_NODES 100000
#define N_EDGES 1600000
#define NEG_SLOPE 0.2f

// bucket = dst >> 7 : 128 nodes per bucket, contiguous node ranges
#define NB_BUCKET 782            // ceil(100000 / 128)
#define ST_CAP 2560              // fixed bucket stride AND LDS cap (mean 2048, 11 sigma)

// ---- workspace layout (bytes) ----
#define OFF_H     0              // N*128 bf16 = 25,600,000
#define OFF_ASRC  25600000       // N*4 f32    =  1,600,000
#define OFF_ADST  27200000       // N*4 f32    =  1,600,000
#define OFF_BCUR  29600000       // 782 int (pad 4096)
#define OFF_TMP   29604096       // 782*2560*4 = 8,007,680
#define OFF_WHT   37611776       // 128*128 bf16 = 32,768  (W^T hi)
#define OFF_WLT   37644544       // 128*128 bf16 = 32,768  (W^T lo residual)
#define OFF_WAH   37677312       // 16*128 bf16 = 4,096    (WA^T hi, rows 8-15 zero)
#define OFF_WAL   37681408       // 16*128 bf16 = 4,096    (WA^T lo)
// total ≈ 37.7 MB

typedef __attribute__((ext_vector_type(8))) __bf16 bf16x8;
typedef __attribute__((ext_vector_type(4))) float  f32x4;
union BF8 { unsigned u32[4]; bf16x8 v; };

__device__ __forceinline__ float leaky(float x) {
    return fmaxf(x, NEG_SLOPE * x);
}
__device__ __forceinline__ float sel4(int h, float a, float b, float c, float d) {
    return h == 0 ? a : (h == 1 ? b : (h == 2 ? c : d));
}
// bf16x2 (packed in a uint) -> float2; .x = low half (even channel)
__device__ __forceinline__ float2 bf2_to_f2(unsigned int u) {
    float2 r;
    r.x = __uint_as_float(u << 16);
    r.y = __uint_as_float(u & 0xffff0000u);
    return r;
}
// round-to-nearest-even fp32 -> bf16 bits
__device__ __forceinline__ unsigned bf16_rne(float f) {
    const unsigned b = __float_as_uint(f);
    return ((b + 0x7FFFu + ((b >> 16) & 1u)) >> 16) & 0xFFFFu;
}
__device__ __forceinline__ float bf16_tof(unsigned hb) {
    return __uint_as_float(hb << 16);
}
// wave-local LDS fence: per-wave stage slices, no block barrier needed
__device__ __forceinline__ void wave_lds_fence() {
    asm volatile("s_waitcnt lgkmcnt(0)" ::: "memory");
    __builtin_amdgcn_sched_barrier(0);
}

// ---------------------------------------------------------------------------
// K0: W prep — split W into bf16 hi/lo [n][k]; WA = W @ Att; zero bcur.
// ---------------------------------------------------------------------------
__global__ __launch_bounds__(256) void wprep_kernel(
    const float* __restrict__ W, const float* __restrict__ att_src,
    const float* __restrict__ att_dst,
    ushort* __restrict__ WhT, ushort* __restrict__ WlT,
    ushort* __restrict__ WAh, ushort* __restrict__ WAl,
    int* __restrict__ bcur)
{
    const int idx = blockIdx.x * 256 + threadIdx.x;   // 0..16383
    const int n = idx >> 7, k = idx & 127;
    const float w  = W[k * 128 + n];
    const unsigned hb = bf16_rne(w);
    const float rs = w - bf16_tof(hb);
    WhT[n * 128 + k] = (ushort)hb;
    WlT[n * 128 + k] = (ushort)bf16_rne(rs);

    if (idx < 2048) {                                  // WA^T: j = 0..15, k
        const int j = idx >> 7;                        // WA column
        float v = 0.f;
        if (j < 8) {
            const int hh = j & 3;
            const float* att = (j < 4) ? att_src : att_dst;
#pragma unroll
            for (int c = 0; c < 32; ++c)
                v = fmaf(W[k * 128 + hh * 32 + c], att[hh * 32 + c], v);
        }
        const unsigned ab = bf16_rne(v);
        WAh[j * 128 + k] = (ushort)ab;
        WAl[j * 128 + k] = (ushort)bf16_rne(v - bf16_tof(ab));
    }
    if (idx < NB_BUCKET) bcur[idx] = 0;
}

// ---------------------------------------------------------------------------
// K1 (FAT, R7 form — proven): blocks 0..255 = scat, 256..1037 = gemm.
// ---------------------------------------------------------------------------
#define S1_EPB 6250
#define FAT_SCAT_BLOCKS 256
#define FAT_GEMM_BLOCKS 782

__global__ __launch_bounds__(256, 2) void fat_kernel(
    // gemm
    const float* __restrict__ x, const ushort* __restrict__ WhT,
    const ushort* __restrict__ WlT, const ushort* __restrict__ WAh,
    const ushort* __restrict__ WAl,
    ushort* __restrict__ h_u16, float* __restrict__ a_src, float* __restrict__ a_dst,
    // scat
    const int* __restrict__ src, const int* __restrict__ dst,
    int* __restrict__ bcur, unsigned int* __restrict__ tmp)
{
    __shared__ int s_cnt[NB_BUCKET];       // scat only
    __shared__ int s_dstash[S1_EPB];       // 25 KB

    const int tid = threadIdx.x;

    if (blockIdx.x < FAT_SCAT_BLOCKS) {
        // ---------------- scat body ----------------
        for (int i = tid; i < NB_BUCKET; i += 256) s_cnt[i] = 0;
        __syncthreads();
        const int e0 = blockIdx.x * S1_EPB;
        for (int i = tid; i < S1_EPB; i += 256) {
            const int d = dst[e0 + i];
            s_dstash[i] = d;
            atomicAdd(&s_cnt[d >> 7], 1);
        }
        __syncthreads();
        for (int b = tid; b < NB_BUCKET; b += 256) {
            const int c = s_cnt[b];
            s_cnt[b] = c ? (b * ST_CAP + atomicAdd(&bcur[b], c)) : 0;
        }
        __syncthreads();
        for (int i = tid; i < S1_EPB; i += 256) {
            const int d = s_dstash[i];
            const int s = src[e0 + i];
            const int p = atomicAdd(&s_cnt[d >> 7], 1);
            tmp[p] = ((unsigned int)s << 7) | (unsigned int)(d & 127);
        }
        return;
    }

    // -------------------- gemm body: 32 rows/wave --------------------
    const int gb   = blockIdx.x - FAT_SCAT_BLOCKS;
    const int wv   = tid >> 6;
    const int lane = tid & 63;
    const int c15  = lane & 15;
    const int kg   = lane >> 4;               // k-octet group 0..3
    const int r0g  = gb * 128 + wv * 32;

    // ---- load x rows, split to bf16 hi/lo A-fragments (registers) ----
    bf16x8 ah[2][4], al[2][4];                // [mt][ks]
#pragma unroll
    for (int mt = 0; mt < 2; ++mt) {
        int row = r0g + mt * 16 + c15;
        row = row < N_NODES ? row : N_NODES - 1;
        const float4* xp = (const float4*)&x[(size_t)row * 128];
#pragma unroll
        for (int ks = 0; ks < 4; ++ks) {
            const int kb = ks * 32 + kg * 8;          // element base within row
            const float4 fa = xp[kb >> 2];
            const float4 fb = xp[(kb >> 2) + 1];
            const float f[8] = {fa.x, fa.y, fa.z, fa.w, fb.x, fb.y, fb.z, fb.w};
            BF8 H, L;
#pragma unroll
            for (int j = 0; j < 4; ++j) {
                const unsigned h0 = bf16_rne(f[2 * j + 0]);
                const unsigned h1 = bf16_rne(f[2 * j + 1]);
                const unsigned l0 = bf16_rne(f[2 * j + 0] - bf16_tof(h0));
                const unsigned l1 = bf16_rne(f[2 * j + 1] - bf16_tof(h1));
                H.u32[j] = h0 | (h1 << 16);
                L.u32[j] = l0 | (l1 << 16);
            }
            ah[mt][ks] = H.v;
            al[mt][ks] = L.v;
        }
    }

    // ---- MFMA main loop ----
    f32x4 acc[2][8];
    f32x4 acca[2];
#pragma unroll
    for (int mt = 0; mt < 2; ++mt) {
        acca[mt] = (f32x4){0.f, 0.f, 0.f, 0.f};
#pragma unroll
        for (int nt = 0; nt < 8; ++nt)
            acc[mt][nt] = (f32x4){0.f, 0.f, 0.f, 0.f};
    }

#pragma unroll
    for (int ks = 0; ks < 4; ++ks) {
        const int kb = ks * 32 + kg * 8;
#pragma unroll
        for (int nt = 0; nt < 8; ++nt) {
            const int col = nt * 16 + c15;
            const bf16x8 bh = *(const bf16x8*)&WhT[col * 128 + kb];
            const bf16x8 bl = *(const bf16x8*)&WlT[col * 128 + kb];
            acc[0][nt] = __builtin_amdgcn_mfma_f32_16x16x32_bf16(ah[0][ks], bh, acc[0][nt], 0, 0, 0);
            acc[1][nt] = __builtin_amdgcn_mfma_f32_16x16x32_bf16(ah[1][ks], bh, acc[1][nt], 0, 0, 0);
            acc[0][nt] = __builtin_amdgcn_mfma_f32_16x16x32_bf16(al[0][ks], bh, acc[0][nt], 0, 0, 0);
            acc[1][nt] = __builtin_amdgcn_mfma_f32_16x16x32_bf16(al[1][ks], bh, acc[1][nt], 0, 0, 0);
            acc[0][nt] = __builtin_amdgcn_mfma_f32_16x16x32_bf16(ah[0][ks], bl, acc[0][nt], 0, 0, 0);
            acc[1][nt] = __builtin_amdgcn_mfma_f32_16x16x32_bf16(ah[1][ks], bl, acc[1][nt], 0, 0, 0);
        }
        // attention columns (8 live cols in a 16-wide fragment)
        const bf16x8 bha = *(const bf16x8*)&WAh[c15 * 128 + kb];
        const bf16x8 bla = *(const bf16x8*)&WAl[c15 * 128 + kb];
        acca[0] = __builtin_amdgcn_mfma_f32_16x16x32_bf16(ah[0][ks], bha, acca[0], 0, 0, 0);
        acca[1] = __builtin_amdgcn_mfma_f32_16x16x32_bf16(ah[1][ks], bha, acca[1], 0, 0, 0);
        acca[0] = __builtin_amdgcn_mfma_f32_16x16x32_bf16(al[0][ks], bha, acca[0], 0, 0, 0);
        acca[1] = __builtin_amdgcn_mfma_f32_16x16x32_bf16(al[1][ks], bha, acca[1], 0, 0, 0);
        acca[0] = __builtin_amdgcn_mfma_f32_16x16x32_bf16(ah[0][ks], bla, acca[0], 0, 0, 0);
        acca[1] = __builtin_amdgcn_mfma_f32_16x16x32_bf16(ah[1][ks], bla, acca[1], 0, 0, 0);
    }

    // ---- epilogue: h bf16 stores + direct a_src/a_dst stores ----
    // C/D layout: col = nt*16 + (lane&15), row = mt*16 + (lane>>4)*4 + reg
#pragma unroll
    for (int mt = 0; mt < 2; ++mt) {
#pragma unroll
        for (int reg = 0; reg < 4; ++reg) {
            const int row = r0g + mt * 16 + kg * 4 + reg;
            if (row >= N_NODES) continue;
#pragma unroll
            for (int nt = 0; nt < 8; ++nt)
                h_u16[(size_t)row * 128 + nt * 16 + c15] =
                    (ushort)bf16_rne(acc[mt][nt][reg]);
            if (c15 < 4)
                a_src[row * 4 + c15] = acca[mt][reg];
            else if (c15 < 8)
                a_dst[row * 4 + (c15 - 4)] = acca[mt][reg];
        }
    }
}

// ---------------------------------------------------------------------------
// K2 (fused phaseB + agg): one block per bucket, 512 threads (8 waves).
// Phase 1 (block-wide): stage tmp->LDS, 128-bin hist, scan, in-LDS csr
// scatter. Phase 2 (per-wave): each wave aggregates 16 of the bucket's 128
// nodes with the proven agg inner loops; csr reads come from LDS.
// Eliminates the phaseB kernel + csr/node_info global round-trips.
// ---------------------------------------------------------------------------
__global__ __launch_bounds__(512) void phaseB_agg_kernel(
    const unsigned int* __restrict__ tmp, const int* __restrict__ bcur,
    const __hip_bfloat162* __restrict__ h_bf,
    const float* __restrict__ a_src, const float* __restrict__ a_dst,
    const float* __restrict__ bias, float* __restrict__ out)
{
    __shared__ unsigned int st[ST_CAP];     // 10.24 KB packed (s<<7 | d&127)
    __shared__ int csr_l[ST_CAP];           // 10.24 KB sorted src
    __shared__ int hist[128];
    __shared__ int cur[128];
    __shared__ int nstart[128];
    __shared__ int wtot[8];
    __shared__ float4 stage[8][128];        // 16 KB, per-wave slices

    const int b    = blockIdx.x;
    const int tid  = threadIdx.x;
    const int lane = tid & 63;
    const int wv   = tid >> 6;
    const int base = b * ST_CAP;
    int cnt = bcur[b];
    cnt = cnt < ST_CAP ? cnt : ST_CAP;

    if (tid < 128) hist[tid] = 0;
    __syncthreads();

    // ---- phase 1a: stage + histogram ----
    for (int i = tid; i < cnt; i += 512) {
        const unsigned int v = tmp[base + i];
        st[i] = v;
        atomicAdd(&hist[v & 127], 1);
    }
    __syncthreads();

    // ---- phase 1b: exclusive scan of 128 bins (first 2 waves) ----
    const int hv = (tid < 128) ? hist[tid] : 0;
    int sv = hv;
#pragma unroll
    for (int off = 1; off < 64; off <<= 1) {
        int u = __shfl_up(sv, off);
        if (lane >= off) sv += u;
    }
    if (tid < 128 && lane == 63) wtot[wv] = sv;
    __syncthreads();
    if (tid < 128) {
        const int wpre = (wv > 0) ? wtot[0] : 0;
        const int excl = wpre + sv - hv;
        cur[tid]    = excl;
        nstart[tid] = excl;
    }
    __syncthreads();

    // ---- phase 1c: in-LDS csr scatter ----
    for (int i = tid; i < cnt; i += 512) {
        const unsigned int v = st[i];
        const int p = atomicAdd(&cur[v & 127], 1);
        csr_l[p] = (int)(v >> 7);
    }
    __syncthreads();

    // ---- phase 2: per-wave aggregation, 16 nodes per wave ----
    const float2 b2 = ((const float2*)bias)[lane];
    const int qw   = lane >> 4;        // edge group 0..3
    const int cpos = lane & 15;        // 8-channel slot within row
    const int hsub = cpos >> 2;        // head of this lane's channels
    const uint4* hp = (const uint4*)h_bf;

    for (int ln = wv * 16; ln < wv * 16 + 16; ++ln) {
        const int node = (b << 7) + ln;
        if (node >= N_NODES) break;
        const int start = nstart[ln];
        const int deg   = hist[ln];

        const float4 ad4 = ((const float4*)a_dst)[node];

        // stage (s, e_head) pairs for up to 64 edges; zeros beyond deg
        float sf = __int_as_float(0);
        float e0 = 0.f, e1 = 0.f, e2 = 0.f, e3 = 0.f;
        if (lane < deg) {
            const int s = csr_l[start + lane];
            sf = __int_as_float(s);
            const float4 as4 = ((const float4*)a_src)[s];
            e0 = __expf(leaky(as4.x + ad4.x));
            e1 = __expf(leaky(as4.y + ad4.y));
            e2 = __expf(leaky(as4.z + ad4.z));
            e3 = __expf(leaky(as4.w + ad4.w));
        }
        stage[wv][lane * 2 + 0] = make_float4(sf, e0, sf, e1);
        stage[wv][lane * 2 + 1] = make_float4(sf, e2, sf, e3);
        wave_lds_fence();

        if (deg <= 64) {
            const float2* sp = (const float2*)&stage[wv][0];

            float acc[8];
#pragma unroll
            for (int i = 0; i < 8; ++i) acc[i] = 0.f;
            float den = 0.f;

            for (int j = 0; j < deg; j += 16) {
#pragma unroll
                for (int u = 0; u < 4; ++u) {
                    const float2 se = sp[(j + u * 4 + qw) * 4 + hsub];
                    const float ev = se.y;
                    const unsigned s = (unsigned)__float_as_int(se.x);
                    const uint4 hvv = hp[(size_t)(s * 16u + (unsigned)cpos)];
                    float2 f;
                    f = bf2_to_f2(hvv.x);
                    acc[0] = fmaf(ev, f.x, acc[0]);
                    acc[1] = fmaf(ev, f.y, acc[1]);
                    f = bf2_to_f2(hvv.y);
                    acc[2] = fmaf(ev, f.x, acc[2]);
                    acc[3] = fmaf(ev, f.y, acc[3]);
                    f = bf2_to_f2(hvv.z);
                    acc[4] = fmaf(ev, f.x, acc[4]);
                    acc[5] = fmaf(ev, f.y, acc[5]);
                    f = bf2_to_f2(hvv.w);
                    acc[6] = fmaf(ev, f.x, acc[6]);
                    acc[7] = fmaf(ev, f.y, acc[7]);
                    den += ev;
                }
            }

            // combine the 4 edge-groups (lanes differ in bits 4,5)
#pragma unroll
            for (int i = 0; i < 8; ++i) acc[i] += __shfl_xor(acc[i], 16);
#pragma unroll
            for (int i = 0; i < 8; ++i) acc[i] += __shfl_xor(acc[i], 32);
            den += __shfl_xor(den, 16);
            den += __shfl_xor(den, 32);

            const float inv = 1.0f / (den + 1e-16f);
#pragma unroll
            for (int i = 0; i < 8; ++i) acc[i] *= inv;

            // redistribute 8-ch-per-lane -> 2-ch-per-lane via wave-local LDS
            if (qw == 0) {
                float4* sf4 = (float4*)&stage[wv][0];
                sf4[cpos * 2 + 0] = make_float4(acc[0], acc[1], acc[2], acc[3]);
                sf4[cpos * 2 + 1] = make_float4(acc[4], acc[5], acc[6], acc[7]);
            }
            wave_lds_fence();
            const float2 v = ((const float2*)&stage[wv][0])[lane];
            float ox = v.x + b2.x;
            float oy = v.y + b2.y;
            ox = ox > 0.f ? ox : __expf(ox) - 1.f;
            oy = oy > 0.f ? oy : __expf(oy) - 1.f;
            ((float2*)out)[(size_t)node * 64 + lane] = make_float2(ox, oy);
        } else {
            // rare fallback: deg > 64
            const int hidx = lane >> 4;
            const float adh = sel4(hidx, ad4.x, ad4.y, ad4.z, ad4.w);
            float2 acc = {0.f, 0.f};
            float  den = 0.f;
            for (int j = 0; j < deg; ++j) {
                const int s = csr_l[start + j];
                const float ash = a_src[s * 4 + hidx];
                const float ex = __expf(leaky(ash + adh));
                const float2 f = __bfloat1622float2(h_bf[(size_t)s * 64 + lane]);
                acc.x += ex * f.x;
                acc.y += ex * f.y;
                den   += ex;
            }
            const float inv = 1.0f / (den + 1e-16f);
            float ox = acc.x * inv + b2.x;
            float oy = acc.y * inv + b2.y;
            ox = ox > 0.f ? ox : expm1f(ox);
            oy = oy > 0.f ? oy : expm1f(oy);
            ((float2*)out)[(size_t)node * 64 + lane] = make_float2(ox, oy);
        }
    }
}

// ---------------------------------------------------------------------------
extern "C" void kernel_launch(void* const* d_in, const int* in_sizes, int n_in,
                              void* d_out, int out_size, void* d_ws, size_t ws_size,
                              hipStream_t stream)
{
    const float* x       = (const float*)d_in[0];
    const int*   ei      = (const int*)  d_in[1];
    const float* W       = (const float*)d_in[2];
    const float* att_src = (const float*)d_in[3];
    const float* att_dst = (const float*)d_in[4];
    const float* bias    = (const float*)d_in[5];
    float*       out     = (float*)d_out;

    char* ws = (char*)d_ws;
    ushort* h_u16 = (ushort*)(ws + OFF_H);
    __hip_bfloat162* h_bf = (__hip_bfloat162*)(ws + OFF_H);
    float* a_src = (float*)(ws + OFF_ASRC);
    float* a_dst = (float*)(ws + OFF_ADST);
    int*   bcur  = (int*)  (ws + OFF_BCUR);
    unsigned int* tmp = (unsigned int*)(ws + OFF_TMP);
    ushort* WhT  = (ushort*)(ws + OFF_WHT);
    ushort* WlT  = (ushort*)(ws + OFF_WLT);
    ushort* WAh  = (ushort*)(ws + OFF_WAH);
    ushort* WAl  = (ushort*)(ws + OFF_WAL);

    const int* srcp = ei;
    const int* dstp = ei + N_EDGES;

    wprep_kernel<<<64, 256, 0, stream>>>(W, att_src, att_dst, WhT, WlT, WAh, WAl, bcur);

    fat_kernel<<<FAT_SCAT_BLOCKS + FAT_GEMM_BLOCKS, 256, 0, stream>>>(
        x, WhT, WlT, WAh, WAl, h_u16, a_src, a_dst,
        srcp, dstp, bcur, tmp);

    phaseB_agg_kernel<<<NB_BUCKET, 512, 0, stream>>>(
        tmp, bcur, h_bf, a_src, a_dst, bias, out);
}

// Round 11
// 249.490 us; speedup vs baseline: 1.0955x; 1.0742x over previous
//
#include <hip/hip_runtime.h>
#include <hip/hip_bf16.h>
#include <math.h>

#define N_NODES 100000
#define N_EDGES 1600000
#define NEG_SLOPE 0.2f

// bucket = dst >> 7 : 128 nodes per bucket, contiguous node ranges
#define NB_BUCKET 782            // ceil(100000 / 128)
#define ST_CAP 2560              // fixed bucket stride AND LDS cap (mean 2048, 11 sigma)

// ---- workspace layout (bytes) ----
#define OFF_H     0              // N*128 bf16 = 25,600,000
#define OFF_ASRC  25600000       // N*4 f32    =  1,600,000
#define OFF_ADST  27200000       // N*4 f32    =  1,600,000
#define OFF_NODE  28800000       // N int2     =    800,000 (start, deg)
#define OFF_BCUR  29600000       // 782 int (pad 4096)
#define OFF_TMP   29604096       // 782*2560*4 = 8,007,680 (tmp AND csr, in-place)
#define OFF_WHT   37611776       // 128*128 bf16 = 32,768  (W^T hi)
#define OFF_WLT   37644544       // 128*128 bf16 = 32,768  (W^T lo residual)
#define OFF_WAH   37677312       // 16*128 bf16 = 4,096    (WA^T hi, rows 8-15 zero)
#define OFF_WAL   37681408       // 16*128 bf16 = 4,096    (WA^T lo)
// total ≈ 37.7 MB

typedef __attribute__((ext_vector_type(8))) __bf16 bf16x8;
typedef __attribute__((ext_vector_type(4))) float  f32x4;
union BF8 { unsigned u32[4]; bf16x8 v; };

__device__ __forceinline__ float leaky(float x) {
    return fmaxf(x, NEG_SLOPE * x);
}
__device__ __forceinline__ float sel4(int h, float a, float b, float c, float d) {
    return h == 0 ? a : (h == 1 ? b : (h == 2 ? c : d));
}
// bf16x2 (packed in a uint) -> float2; .x = low half (even channel)
__device__ __forceinline__ float2 bf2_to_f2(unsigned int u) {
    float2 r;
    r.x = __uint_as_float(u << 16);
    r.y = __uint_as_float(u & 0xffff0000u);
    return r;
}
// round-to-nearest-even fp32 -> bf16 bits
__device__ __forceinline__ unsigned bf16_rne(float f) {
    const unsigned b = __float_as_uint(f);
    return ((b + 0x7FFFu + ((b >> 16) & 1u)) >> 16) & 0xFFFFu;
}
__device__ __forceinline__ float bf16_tof(unsigned hb) {
    return __uint_as_float(hb << 16);
}
// wave-local LDS fence: per-wave stage slices, no block barrier needed
__device__ __forceinline__ void wave_lds_fence() {
    asm volatile("s_waitcnt lgkmcnt(0)" ::: "memory");
    __builtin_amdgcn_sched_barrier(0);
}

// ---------------------------------------------------------------------------
// K0: W prep — split W into bf16 hi/lo [n][k]; WA = W @ Att; zero bcur.
// ---------------------------------------------------------------------------
__global__ __launch_bounds__(256) void wprep_kernel(
    const float* __restrict__ W, const float* __restrict__ att_src,
    const float* __restrict__ att_dst,
    ushort* __restrict__ WhT, ushort* __restrict__ WlT,
    ushort* __restrict__ WAh, ushort* __restrict__ WAl,
    int* __restrict__ bcur)
{
    const int idx = blockIdx.x * 256 + threadIdx.x;   // 0..16383
    const int n = idx >> 7, k = idx & 127;
    const float w  = W[k * 128 + n];
    const unsigned hb = bf16_rne(w);
    const float rs = w - bf16_tof(hb);
    WhT[n * 128 + k] = (ushort)hb;
    WlT[n * 128 + k] = (ushort)bf16_rne(rs);

    if (idx < 2048) {                                  // WA^T: j = 0..15, k
        const int j = idx >> 7;                        // WA column
        float v = 0.f;
        if (j < 8) {
            const int hh = j & 3;
            const float* att = (j < 4) ? att_src : att_dst;
#pragma unroll
            for (int c = 0; c < 32; ++c)
                v = fmaf(W[k * 128 + hh * 32 + c], att[hh * 32 + c], v);
        }
        const unsigned ab = bf16_rne(v);
        WAh[j * 128 + k] = (ushort)ab;
        WAl[j * 128 + k] = (ushort)bf16_rne(v - bf16_tof(ab));
    }
    if (idx < NB_BUCKET) bcur[idx] = 0;
}

// ---------------------------------------------------------------------------
// K1 (FAT, R7 form — proven): blocks 0..255 = scat, 256..1037 = gemm.
// ---------------------------------------------------------------------------
#define S1_EPB 6250
#define FAT_SCAT_BLOCKS 256
#define FAT_GEMM_BLOCKS 782

__global__ __launch_bounds__(256, 2) void fat_kernel(
    // gemm
    const float* __restrict__ x, const ushort* __restrict__ WhT,
    const ushort* __restrict__ WlT, const ushort* __restrict__ WAh,
    const ushort* __restrict__ WAl,
    ushort* __restrict__ h_u16, float* __restrict__ a_src, float* __restrict__ a_dst,
    // scat
    const int* __restrict__ src, const int* __restrict__ dst,
    int* __restrict__ bcur, unsigned int* __restrict__ tmp)
{
    __shared__ int s_cnt[NB_BUCKET];       // scat only
    __shared__ int s_dstash[S1_EPB];       // 25 KB

    const int tid = threadIdx.x;

    if (blockIdx.x < FAT_SCAT_BLOCKS) {
        // ---------------- scat body ----------------
        for (int i = tid; i < NB_BUCKET; i += 256) s_cnt[i] = 0;
        __syncthreads();
        const int e0 = blockIdx.x * S1_EPB;
        for (int i = tid; i < S1_EPB; i += 256) {
            const int d = dst[e0 + i];
            s_dstash[i] = d;
            atomicAdd(&s_cnt[d >> 7], 1);
        }
        __syncthreads();
        for (int b = tid; b < NB_BUCKET; b += 256) {
            const int c = s_cnt[b];
            s_cnt[b] = c ? (b * ST_CAP + atomicAdd(&bcur[b], c)) : 0;
        }
        __syncthreads();
        for (int i = tid; i < S1_EPB; i += 256) {
            const int d = s_dstash[i];
            const int s = src[e0 + i];
            const int p = atomicAdd(&s_cnt[d >> 7], 1);
            tmp[p] = ((unsigned int)s << 7) | (unsigned int)(d & 127);
        }
        return;
    }

    // -------------------- gemm body: 32 rows/wave --------------------
    const int gb   = blockIdx.x - FAT_SCAT_BLOCKS;
    const int wv   = tid >> 6;
    const int lane = tid & 63;
    const int c15  = lane & 15;
    const int kg   = lane >> 4;               // k-octet group 0..3
    const int r0g  = gb * 128 + wv * 32;

    // ---- load x rows, split to bf16 hi/lo A-fragments (registers) ----
    bf16x8 ah[2][4], al[2][4];                // [mt][ks]
#pragma unroll
    for (int mt = 0; mt < 2; ++mt) {
        int row = r0g + mt * 16 + c15;
        row = row < N_NODES ? row : N_NODES - 1;
        const float4* xp = (const float4*)&x[(size_t)row * 128];
#pragma unroll
        for (int ks = 0; ks < 4; ++ks) {
            const int kb = ks * 32 + kg * 8;          // element base within row
            const float4 fa = xp[kb >> 2];
            const float4 fb = xp[(kb >> 2) + 1];
            const float f[8] = {fa.x, fa.y, fa.z, fa.w, fb.x, fb.y, fb.z, fb.w};
            BF8 H, L;
#pragma unroll
            for (int j = 0; j < 4; ++j) {
                const unsigned h0 = bf16_rne(f[2 * j + 0]);
                const unsigned h1 = bf16_rne(f[2 * j + 1]);
                const unsigned l0 = bf16_rne(f[2 * j + 0] - bf16_tof(h0));
                const unsigned l1 = bf16_rne(f[2 * j + 1] - bf16_tof(h1));
                H.u32[j] = h0 | (h1 << 16);
                L.u32[j] = l0 | (l1 << 16);
            }
            ah[mt][ks] = H.v;
            al[mt][ks] = L.v;
        }
    }

    // ---- MFMA main loop ----
    f32x4 acc[2][8];
    f32x4 acca[2];
#pragma unroll
    for (int mt = 0; mt < 2; ++mt) {
        acca[mt] = (f32x4){0.f, 0.f, 0.f, 0.f};
#pragma unroll
        for (int nt = 0; nt < 8; ++nt)
            acc[mt][nt] = (f32x4){0.f, 0.f, 0.f, 0.f};
    }

#pragma unroll
    for (int ks = 0; ks < 4; ++ks) {
        const int kb = ks * 32 + kg * 8;
#pragma unroll
        for (int nt = 0; nt < 8; ++nt) {
            const int col = nt * 16 + c15;
            const bf16x8 bh = *(const bf16x8*)&WhT[col * 128 + kb];
            const bf16x8 bl = *(const bf16x8*)&WlT[col * 128 + kb];
            acc[0][nt] = __builtin_amdgcn_mfma_f32_16x16x32_bf16(ah[0][ks], bh, acc[0][nt], 0, 0, 0);
            acc[1][nt] = __builtin_amdgcn_mfma_f32_16x16x32_bf16(ah[1][ks], bh, acc[1][nt], 0, 0, 0);
            acc[0][nt] = __builtin_amdgcn_mfma_f32_16x16x32_bf16(al[0][ks], bh, acc[0][nt], 0, 0, 0);
            acc[1][nt] = __builtin_amdgcn_mfma_f32_16x16x32_bf16(al[1][ks], bh, acc[1][nt], 0, 0, 0);
            acc[0][nt] = __builtin_amdgcn_mfma_f32_16x16x32_bf16(ah[0][ks], bl, acc[0][nt], 0, 0, 0);
            acc[1][nt] = __builtin_amdgcn_mfma_f32_16x16x32_bf16(ah[1][ks], bl, acc[1][nt], 0, 0, 0);
        }
        // attention columns (8 live cols in a 16-wide fragment)
        const bf16x8 bha = *(const bf16x8*)&WAh[c15 * 128 + kb];
        const bf16x8 bla = *(const bf16x8*)&WAl[c15 * 128 + kb];
        acca[0] = __builtin_amdgcn_mfma_f32_16x16x32_bf16(ah[0][ks], bha, acca[0], 0, 0, 0);
        acca[1] = __builtin_amdgcn_mfma_f32_16x16x32_bf16(ah[1][ks], bha, acca[1], 0, 0, 0);
        acca[0] = __builtin_amdgcn_mfma_f32_16x16x32_bf16(al[0][ks], bha, acca[0], 0, 0, 0);
        acca[1] = __builtin_amdgcn_mfma_f32_16x16x32_bf16(al[1][ks], bha, acca[1], 0, 0, 0);
        acca[0] = __builtin_amdgcn_mfma_f32_16x16x32_bf16(ah[0][ks], bla, acca[0], 0, 0, 0);
        acca[1] = __builtin_amdgcn_mfma_f32_16x16x32_bf16(ah[1][ks], bla, acca[1], 0, 0, 0);
    }

    // ---- epilogue: h bf16 stores + direct a_src/a_dst stores ----
    // C/D layout: col = nt*16 + (lane&15), row = mt*16 + (lane>>4)*4 + reg
#pragma unroll
    for (int mt = 0; mt < 2; ++mt) {
#pragma unroll
        for (int reg = 0; reg < 4; ++reg) {
            const int row = r0g + mt * 16 + kg * 4 + reg;
            if (row >= N_NODES) continue;
#pragma unroll
            for (int nt = 0; nt < 8; ++nt)
                h_u16[(size_t)row * 128 + nt * 16 + c15] =
                    (ushort)bf16_rne(acc[mt][nt][reg]);
            if (c15 < 4)
                a_src[row * 4 + c15] = acca[mt][reg];
            else if (c15 < 8)
                a_dst[row * 4 + (c15 - 4)] = acca[mt][reg];
        }
    }
}

// ---------------------------------------------------------------------------
// K2: per-bucket finalize (R7 form — proven). One block per bucket.
// ---------------------------------------------------------------------------
__global__ __launch_bounds__(256) void phaseB_kernel(
    const unsigned int* __restrict__ tmp, const int* __restrict__ bcur,
    int2* __restrict__ node_info, int* __restrict__ csr)
{
    __shared__ unsigned int st[ST_CAP];
    __shared__ int hist[128];
    __shared__ int cur[128];
    __shared__ int wtot[4];

    const int b    = blockIdx.x;
    const int tid  = threadIdx.x;
    const int lane = tid & 63;
    const int wv   = tid >> 6;
    const int base = b * ST_CAP;
    int cnt = bcur[b];
    cnt = cnt < ST_CAP ? cnt : ST_CAP;

    if (tid < 128) hist[tid] = 0;
    __syncthreads();

    // stage (everything fits) + histogram
    for (int i = tid; i < cnt; i += 256) {
        const unsigned int v = tmp[base + i];
        st[i] = v;
        atomicAdd(&hist[v & 127], 1);
    }
    __syncthreads();

    // exclusive scan of 128 bins across first 2 waves (uniform barriers)
    const int hv = (tid < 128) ? hist[tid] : 0;
    int sv = hv;
#pragma unroll
    for (int off = 1; off < 64; off <<= 1) {
        int u = __shfl_up(sv, off);
        if (lane >= off) sv += u;
    }
    if (lane == 63) wtot[wv] = sv;
    __syncthreads();
    const int wpre = (wv > 0 ? wtot[0] : 0) + (wv > 1 ? wtot[1] : 0) + (wv > 2 ? wtot[2] : 0);
    if (tid < 128) {
        const int excl = wpre + sv - hv;
        cur[tid] = excl;
        const int node = (b << 7) + tid;
        if (node < N_NODES) node_info[node] = make_int2(base + excl, hv);
    }
    __syncthreads();

    // scatter src into bucket-local csr region (in-place over tmp: safe)
    for (int i = tid; i < cnt; i += 256) {
        const unsigned int v = st[i];
        const int p = atomicAdd(&cur[v & 127], 1);
        csr[base + p] = (int)(v >> 7);
    }
}

// ---------------------------------------------------------------------------
// K3: fused softmax + aggregate + ELU, v4: TWO nodes per wave.
// Stage both nodes' (s, exp) pairs before a single fence; interleave both
// gather loops (8 independent outstanding loads); parallel redistribution
// (qw==0 lanes write node A's result, qw==1 lanes write node B's).
// Per-node arithmetic identical to v2 -> bit-identical output.
// ---------------------------------------------------------------------------
__global__ __launch_bounds__(256, 4) void gat_agg_kernel(
    const int* __restrict__ csr_src, const int2* __restrict__ node_info,
    const __hip_bfloat162* __restrict__ h_bf,
    const float* __restrict__ a_src, const float* __restrict__ a_dst,
    const float* __restrict__ bias, float* __restrict__ out)
{
    __shared__ float4 stage[4][256];       // per-wave: A in [0..127], B in [128..255]

    const int wv    = threadIdx.x >> 6;
    const int lane  = threadIdx.x & 63;
    const int nodeA = (blockIdx.x * 4 + wv) * 2;
    const int nodeB = nodeA + 1;

    const int2 nfA = node_info[nodeA];
    const int2 nfB = node_info[nodeB];
    const int startA = nfA.x, degA = nfA.y;
    const int startB = nfB.x, degB = nfB.y;

    const float4 adA = ((const float4*)a_dst)[nodeA];
    const float4 adB = ((const float4*)a_dst)[nodeB];

    // ---- stage both nodes' (s, e_head) pairs; zeros beyond deg ----
    {
        float sf = __int_as_float(0);
        float e0 = 0.f, e1 = 0.f, e2 = 0.f, e3 = 0.f;
        if (lane < degA) {
            const int s = csr_src[startA + lane];
            sf = __int_as_float(s);
            const float4 as4 = ((const float4*)a_src)[s];
            e0 = __expf(leaky(as4.x + adA.x));
            e1 = __expf(leaky(as4.y + adA.y));
            e2 = __expf(leaky(as4.z + adA.z));
            e3 = __expf(leaky(as4.w + adA.w));
        }
        stage[wv][lane * 2 + 0] = make_float4(sf, e0, sf, e1);
        stage[wv][lane * 2 + 1] = make_float4(sf, e2, sf, e3);
    }
    {
        float sf = __int_as_float(0);
        float e0 = 0.f, e1 = 0.f, e2 = 0.f, e3 = 0.f;
        if (lane < degB) {
            const int s = csr_src[startB + lane];
            sf = __int_as_float(s);
            const float4 as4 = ((const float4*)a_src)[s];
            e0 = __expf(leaky(as4.x + adB.x));
            e1 = __expf(leaky(as4.y + adB.y));
            e2 = __expf(leaky(as4.z + adB.z));
            e3 = __expf(leaky(as4.w + adB.w));
        }
        stage[wv][256 / 2 + lane * 2 + 0] = make_float4(sf, e0, sf, e1);
        stage[wv][256 / 2 + lane * 2 + 1] = make_float4(sf, e2, sf, e3);
    }
    wave_lds_fence();

    const int qw   = lane >> 4;        // edge group 0..3
    const int cpos = lane & 15;        // 8-channel slot within row
    const int hsub = cpos >> 2;        // head of this lane's channels
    const float2* spA = (const float2*)&stage[wv][0];
    const float2* spB = (const float2*)&stage[wv][128];
    const uint4*  hp  = (const uint4*)h_bf;
    const float2  b2  = ((const float2*)bias)[lane];

    const bool okA = degA <= 64;
    const bool okB = degB <= 64;

    float accA[8], accB[8];
#pragma unroll
    for (int i = 0; i < 8; ++i) { accA[i] = 0.f; accB[i] = 0.f; }
    float denA = 0.f, denB = 0.f;

    if (okA && okB) {
        const int degM = degA > degB ? degA : degB;
        for (int j = 0; j < degM; j += 16) {
            if (j < degA) {
#pragma unroll
                for (int u = 0; u < 4; ++u) {
                    const float2 se = spA[(j + u * 4 + qw) * 4 + hsub];
                    const float ev = se.y;
                    const unsigned s = (unsigned)__float_as_int(se.x);
                    const uint4 hv = hp[(size_t)(s * 16u + (unsigned)cpos)];
                    float2 f;
                    f = bf2_to_f2(hv.x);
                    accA[0] = fmaf(ev, f.x, accA[0]);
                    accA[1] = fmaf(ev, f.y, accA[1]);
                    f = bf2_to_f2(hv.y);
                    accA[2] = fmaf(ev, f.x, accA[2]);
                    accA[3] = fmaf(ev, f.y, accA[3]);
                    f = bf2_to_f2(hv.z);
                    accA[4] = fmaf(ev, f.x, accA[4]);
                    accA[5] = fmaf(ev, f.y, accA[5]);
                    f = bf2_to_f2(hv.w);
                    accA[6] = fmaf(ev, f.x, accA[6]);
                    accA[7] = fmaf(ev, f.y, accA[7]);
                    denA += ev;
                }
            }
            if (j < degB) {
#pragma unroll
                for (int u = 0; u < 4; ++u) {
                    const float2 se = spB[(j + u * 4 + qw) * 4 + hsub];
                    const float ev = se.y;
                    const unsigned s = (unsigned)__float_as_int(se.x);
                    const uint4 hv = hp[(size_t)(s * 16u + (unsigned)cpos)];
                    float2 f;
                    f = bf2_to_f2(hv.x);
                    accB[0] = fmaf(ev, f.x, accB[0]);
                    accB[1] = fmaf(ev, f.y, accB[1]);
                    f = bf2_to_f2(hv.y);
                    accB[2] = fmaf(ev, f.x, accB[2]);
                    accB[3] = fmaf(ev, f.y, accB[3]);
                    f = bf2_to_f2(hv.z);
                    accB[4] = fmaf(ev, f.x, accB[4]);
                    accB[5] = fmaf(ev, f.y, accB[5]);
                    f = bf2_to_f2(hv.w);
                    accB[6] = fmaf(ev, f.x, accB[6]);
                    accB[7] = fmaf(ev, f.y, accB[7]);
                    denB += ev;
                }
            }
        }

        // combine the 4 edge-groups for both nodes
#pragma unroll
        for (int i = 0; i < 8; ++i) {
            accA[i] += __shfl_xor(accA[i], 16);
            accA[i] += __shfl_xor(accA[i], 32);
            accB[i] += __shfl_xor(accB[i], 16);
            accB[i] += __shfl_xor(accB[i], 32);
        }
        denA += __shfl_xor(denA, 16);
        denA += __shfl_xor(denA, 32);
        denB += __shfl_xor(denB, 16);
        denB += __shfl_xor(denB, 32);

        const float invA = 1.0f / (denA + 1e-16f);
        const float invB = 1.0f / (denB + 1e-16f);
#pragma unroll
        for (int i = 0; i < 8; ++i) { accA[i] *= invA; accB[i] *= invB; }

        // parallel redistribution: qw==0 writes A, qw==1 writes B
        float4* sf4 = (float4*)&stage[wv][0];
        if (qw == 0) {
            sf4[cpos * 2 + 0] = make_float4(accA[0], accA[1], accA[2], accA[3]);
            sf4[cpos * 2 + 1] = make_float4(accA[4], accA[5], accA[6], accA[7]);
        } else if (qw == 1) {
            sf4[32 + cpos * 2 + 0] = make_float4(accB[0], accB[1], accB[2], accB[3]);
            sf4[32 + cpos * 2 + 1] = make_float4(accB[4], accB[5], accB[6], accB[7]);
        }
        wave_lds_fence();
        const float2 vA = ((const float2*)&stage[wv][0])[lane];
        const float2 vB = ((const float2*)&stage[wv][32])[lane];
        float ax = vA.x + b2.x, ay = vA.y + b2.y;
        float bx = vB.x + b2.x, by = vB.y + b2.y;
        ax = ax > 0.f ? ax : __expf(ax) - 1.f;
        ay = ay > 0.f ? ay : __expf(ay) - 1.f;
        bx = bx > 0.f ? bx : __expf(bx) - 1.f;
        by = by > 0.f ? by : __expf(by) - 1.f;
        ((float2*)out)[(size_t)nodeA * 64 + lane] = make_float2(ax, ay);
        ((float2*)out)[(size_t)nodeB * 64 + lane] = make_float2(bx, by);
        return;
    }

    // ---- rare path: at least one node has deg > 64 — process each node
    // with the proven serial fallback (or single-node fast path).
    const int hidx = lane >> 4;
#pragma unroll
    for (int which = 0; which < 2; ++which) {
        const int node  = which ? nodeB : nodeA;
        const int start = which ? startB : startA;
        const int deg   = which ? degB : degA;
        const float4 ad4 = which ? adB : adA;
        const float adh = sel4(hidx, ad4.x, ad4.y, ad4.z, ad4.w);
        float2 acc = {0.f, 0.f};
        float  den = 0.f;
        for (int j = 0; j < deg; ++j) {
            const int s = csr_src[start + j];
            const float ash = a_src[s * 4 + hidx];
            const float ex = __expf(leaky(ash + adh));
            const float2 f = __bfloat1622float2(h_bf[(size_t)s * 64 + lane]);
            acc.x += ex * f.x;
            acc.y += ex * f.y;
            den   += ex;
        }
        const float inv = 1.0f / (den + 1e-16f);
        float ox = acc.x * inv + b2.x;
        float oy = acc.y * inv + b2.y;
        ox = ox > 0.f ? ox : expm1f(ox);
        oy = oy > 0.f ? oy : expm1f(oy);
        ((float2*)out)[(size_t)node * 64 + lane] = make_float2(ox, oy);
    }
}

// ---------------------------------------------------------------------------
extern "C" void kernel_launch(void* const* d_in, const int* in_sizes, int n_in,
                              void* d_out, int out_size, void* d_ws, size_t ws_size,
                              hipStream_t stream)
{
    const float* x       = (const float*)d_in[0];
    const int*   ei      = (const int*)  d_in[1];
    const float* W       = (const float*)d_in[2];
    const float* att_src = (const float*)d_in[3];
    const float* att_dst = (const float*)d_in[4];
    const float* bias    = (const float*)d_in[5];
    float*       out     = (float*)d_out;

    char* ws = (char*)d_ws;
    ushort* h_u16 = (ushort*)(ws + OFF_H);
    __hip_bfloat162* h_bf = (__hip_bfloat162*)(ws + OFF_H);
    float* a_src = (float*)(ws + OFF_ASRC);
    float* a_dst = (float*)(ws + OFF_ADST);
    int2*  ninfo = (int2*) (ws + OFF_NODE);
    int*   bcur  = (int*)  (ws + OFF_BCUR);
    unsigned int* tmp = (unsigned int*)(ws + OFF_TMP);
    int*   csr   = (int*)  (ws + OFF_TMP);   // in-place: csr overwrites tmp
    ushort* WhT  = (ushort*)(ws + OFF_WHT);
    ushort* WlT  = (ushort*)(ws + OFF_WLT);
    ushort* WAh  = (ushort*)(ws + OFF_WAH);
    ushort* WAl  = (ushort*)(ws + OFF_WAL);

    const int* srcp = ei;
    const int* dstp = ei + N_EDGES;

    wprep_kernel<<<64, 256, 0, stream>>>(W, att_src, att_dst, WhT, WlT, WAh, WAl, bcur);

    fat_kernel<<<FAT_SCAT_BLOCKS + FAT_GEMM_BLOCKS, 256, 0, stream>>>(
        x, WhT, WlT, WAh, WAl, h_u16, a_src, a_dst,
        srcp, dstp, bcur, tmp);

    phaseB_kernel<<<NB_BUCKET, 256, 0, stream>>>(tmp, bcur, ninfo, csr);

    gat_agg_kernel<<<N_NODES / 8, 256, 0, stream>>>(
        csr, ninfo, h_bf, a_src, a_dst, bias, out);
}